// Round 5
// baseline (418.387 us; speedup 1.0000x reference)
//
#include <hip/hip_runtime.h>
#include <math.h>

// TemporalEncoder: out[t, b, d] = (t == floor(sigmoid(x[b,d]) * (T-1))) ? 1 : 0
// B=256, D=4096, T=100. Output 419 MB fp32 -> pure write-BW bound.
//
// Structure (two passes, d_ws holds spike times as uchar):
//   Pass 1: spike times -> d_ws (1 MB, L2-resident afterwards; R2 counters
//           proved FETCH_SIZE ~0.5 MB across all 100 planes).
//   Pass 2: persistent sequential-stream writer with FULL-LINE NONTEMPORAL
//           stores (R6).
//
// Counter-verified model of the write path:
//   - Regular stores allocate dirty L2 lines; HBM sees the dirty-EVICTION
//     stream, which ceilings at ~3.0-3.4 TB/s. Four different writer
//     structures (R0 short blocks / R3 strided / R4 4-chunk / R5 persistent
//     pipelined) all landed in that same band -> not a scheduling limit.
//   - rocclr fillBuffer: 6.2 TB/s at 10% occupancy -> streaming full-line
//     writes that bypass the allocate/evict path.
//   - R2: nt stores with lanes at 64-B stride -> quarter-covered lines, no
//     L2 merging -> 2.2x WRITE_SIZE amplification, 2.7 TB/s. The layout was
//     the bug, not nt: nt requires each instruction to cover FULL lines.
//   - R6: nt + lane-coalesced layout: each wave store = 1 KB contiguous =
//     16 complete 64-B lines per instruction. Expect WRITE_SIZE 1.0x and
//     fill-class bandwidth.

typedef __attribute__((ext_vector_type(4))) float f32x4;

__device__ __forceinline__ float sigmoidf_(float x) {
    return 1.0f / (1.0f + expf(-x));  // matches f32 expit to 0 ulp vs np ref (R1)
}

__device__ __forceinline__ f32x4 onehot4_(unsigned int sw, unsigned int tu) {
    f32x4 o;
    o.x = (((sw      ) & 0xffu) == tu) ? 1.0f : 0.0f;
    o.y = (((sw >>  8) & 0xffu) == tu) ? 1.0f : 0.0f;
    o.z = (((sw >> 16) & 0xffu) == tu) ? 1.0f : 0.0f;
    o.w = (((sw >> 24)        ) == tu) ? 1.0f : 0.0f;
    return o;
}

__global__ __launch_bounds__(256) void spike_time_kernel(
    const float* __restrict__ x, unsigned char* __restrict__ st,
    int n, float tm1) {
    const int e = (blockIdx.x * 256 + threadIdx.x) * 4;
    if (e + 3 < n) {
        f32x4 v = *reinterpret_cast<const f32x4*>(x + e);
        uchar4 s;
        s.x = (unsigned char)(int)(sigmoidf_(v.x) * tm1);
        s.y = (unsigned char)(int)(sigmoidf_(v.y) * tm1);
        s.z = (unsigned char)(int)(sigmoidf_(v.z) * tm1);
        s.w = (unsigned char)(int)(sigmoidf_(v.w) * tm1);
        *reinterpret_cast<uchar4*>(st + e) = s;
    } else {
        for (int i = e; i < n; ++i)
            st[i] = (unsigned char)(int)(sigmoidf_(x[i]) * tm1);
    }
}

// Pass 2: persistent streamer. Chunk = 1024 elems (4 KB). Each block owns
// `cpb` CONTIGUOUS chunks; per iteration each thread does one uint st-load
// (for the NEXT chunk, pipelined, cached/L2-hit) and one FULL-LINE
// nontemporal f32x4 store (current chunk). Requires n % 1024 == 0.
__global__ __launch_bounds__(256) void write_onehot_persist_kernel(
    const unsigned char* __restrict__ st, float* __restrict__ out,
    int n, int total_chunks, int cpb) {
    const int cpp = n >> 10;                 // chunks per t-plane
    const int c0 = blockIdx.x * cpb;
    int cend = c0 + cpb;
    if (cend > total_chunks) cend = total_chunks;
    if (c0 >= cend) return;

    const int lane4 = threadIdx.x * 4;       // elem offset within chunk
    int t  = c0 / cpp;                       // once per block, uniform
    int lc = c0 - t * cpp;                   // chunk index within plane

    // software pipeline: st word for the current chunk, loaded one iter ahead
    unsigned int s_next =
        *reinterpret_cast<const unsigned int*>(st + (lc << 10) + lane4);
    float* op = out + (size_t)c0 * 1024 + lane4;

    for (int c = c0; c < cend; ++c) {
        const unsigned int s_cur = s_next;
        const unsigned int tu = (unsigned int)t;
        // advance plane-local position (uniform, no division)
        int lc_n = lc + 1, t_n = t;
        if (lc_n == cpp) { lc_n = 0; ++t_n; }
        if (c + 1 < cend)
            s_next = *reinterpret_cast<const unsigned int*>(
                st + (lc_n << 10) + lane4);
        __builtin_nontemporal_store(onehot4_(s_cur, tu),
                                    reinterpret_cast<f32x4*>(op));
        op += 1024;
        lc = lc_n; t = t_n;
    }
}

// Fallback if d_ws is too small, T doesn't fit in a byte, or n % 1024 != 0.
__global__ __launch_bounds__(256) void fused_onehot_kernel(
    const float* __restrict__ x, float* __restrict__ out, int n, float tm1) {
    const int t = blockIdx.y;
    const int e = (blockIdx.x * 256 + threadIdx.x) * 4;
    if (e + 3 < n) {
        f32x4 v = *reinterpret_cast<const f32x4*>(x + e);
        f32x4 o;
        o.x = ((int)(sigmoidf_(v.x) * tm1) == t) ? 1.0f : 0.0f;
        o.y = ((int)(sigmoidf_(v.y) * tm1) == t) ? 1.0f : 0.0f;
        o.z = ((int)(sigmoidf_(v.z) * tm1) == t) ? 1.0f : 0.0f;
        o.w = ((int)(sigmoidf_(v.w) * tm1) == t) ? 1.0f : 0.0f;
        *reinterpret_cast<f32x4*>(out + (size_t)t * n + e) = o;
    } else {
        for (int i = e; i < n; ++i)
            out[(size_t)t * n + i] = ((int)(sigmoidf_(x[i]) * tm1) == t) ? 1.0f : 0.0f;
    }
}

extern "C" void kernel_launch(void* const* d_in, const int* in_sizes, int n_in,
                              void* d_out, int out_size, void* d_ws, size_t ws_size,
                              hipStream_t stream) {
    const float* x = (const float*)d_in[0];
    float* out = (float*)d_out;
    const int n = in_sizes[0];        // B*D = 1048576
    const int T = out_size / n;       // 100
    const float tm1 = (float)(T - 1);

    const int n4 = (n + 3) / 4;
    const int blocks4 = (n4 + 255) / 256;     // pass-1 / fused grid

    if (ws_size >= (size_t)n && T <= 256 && (n & 1023) == 0) {
        unsigned char* st = (unsigned char*)d_ws;
        spike_time_kernel<<<blocks4, 256, 0, stream>>>(x, st, n, tm1);
        const int total_chunks = (int)(((size_t)T * n) >> 10);  // 102400
        const int target_blocks = 1024;
        const int cpb = (total_chunks + target_blocks - 1) / target_blocks; // 100
        const int blocks = (total_chunks + cpb - 1) / cpb;                  // 1024
        write_onehot_persist_kernel<<<blocks, 256, 0, stream>>>(
            st, out, n, total_chunks, cpb);
    } else {
        dim3 grid(blocks4, T);
        fused_onehot_kernel<<<grid, 256, 0, stream>>>(x, out, n, tm1);
    }
}